// Round 1
// baseline (3171.586 us; speedup 1.0000x reference)
//
#include <hip/hip_runtime.h>
#include <hip/hip_bf16.h>
#include <cstdint>

// B=256, T=512, D_IN=256, D_H=512, D_P=512. Inputs/outputs are FLOAT32.
// Internals run in bf16 MFMA with f32 accumulate.
#define RB   256
#define RT   512
#define ROWS (RB*RT)   // 131072

typedef __attribute__((ext_vector_type(8))) short bf16x8;
typedef __attribute__((ext_vector_type(4))) short s16x4;
typedef __attribute__((ext_vector_type(4))) float f32x4;

#define DEV static __device__ __forceinline__

DEV float bf2f(unsigned short u){
  union { unsigned int i; float f; } v; v.i = ((unsigned int)u) << 16; return v.f;
}
DEV float blo(unsigned int u){
  union { unsigned int i; float f; } v; v.i = u << 16; return v.f;
}
DEV float bhi(unsigned int u){
  union { unsigned int i; float f; } v; v.i = u & 0xffff0000u; return v.f;
}
DEV unsigned short f2bf(float f){
  union { float f; unsigned int i; } v; v.f = f;
  unsigned int x = v.i;
  return (unsigned short)((x + 0x7fffu + ((x >> 16) & 1u)) >> 16);   // RNE
}
DEV unsigned int cvt_pk_bf16(float lo, float hi){   // RNE, bit-identical to f2bf
  unsigned int r;
  asm("v_cvt_pk_bf16_f32 %0, %1, %2" : "=v"(r) : "v"(lo), "v"(hi));
  return r;
}
DEV float tanh_fast(float x){
  // No clamp needed: e=inf -> rcp=0 -> 1.0; e=0 -> rcp(1)=1 -> -1.0 (exact saturation).
  float e  = __expf(2.f * x);
  return 1.f - 2.f * __builtin_amdgcn_rcpf(e + 1.f);
}
DEV float sigmoid_fast(float x){
  float xc = fminf(fmaxf(x, -30.f), 30.f);
  return __builtin_amdgcn_rcpf(1.f + __expf(-xc));
}
DEV void gl_lds16(const void* g, void* l){
  __builtin_amdgcn_global_load_lds(
      (const __attribute__((address_space(1))) unsigned int*)g,
      (__attribute__((address_space(3))) unsigned int*)l, 16, 0, 0);
}

// ---------------------------------------------------------------------------
// f32 -> bf16 conversion of all 15 input tensors (one launch, 4 elems/thread).
// ---------------------------------------------------------------------------
struct ConvArgs {
  const float* src[15];
  unsigned short* dst[15];
  long pre[16];          // prefix sums in 4-element chunks
};

__global__ __launch_bounds__(256) void conv_k(ConvArgs a, long total)
{
  long stride = (long)gridDim.x * blockDim.x;
  for (long idx = (long)blockIdx.x * blockDim.x + threadIdx.x; idx < total; idx += stride){
    int t = 0;
    #pragma unroll
    for (int j = 0; j < 14; j++) t += (idx >= a.pre[j + 1]) ? 1 : 0;
    long local = idx - a.pre[t];
    float4 v = ((const float4*)a.src[t])[local];
    s16x4 o;
    o[0] = (short)f2bf(v.x); o[1] = (short)f2bf(v.y);
    o[2] = (short)f2bf(v.z); o[3] = (short)f2bf(v.w);
    ((s16x4*)a.dst[t])[local] = o;
  }
}

// ---------------------------------------------------------------------------
// W_hh tail repack: K-slices {2,5,8,11,14,15} into fragment-ordered layout so
// recur_k's per-step A-frag loads are perfectly lane-coalesced L2 reads.
// Wt frag index fi = w*24 + ks6*4 + nt; Wt[(fi*64 + l)*8 .. +8] = A-frag(w,nt,ks6,l).
// ---------------------------------------------------------------------------
__global__ __launch_bounds__(256) void wtail_k(
    const unsigned short* __restrict__ Whh, unsigned short* __restrict__ Wt)
{
  static const int kst[6] = {2, 5, 8, 11, 14, 15};
  int id = blockIdx.x * 256 + threadIdx.x;   // 0 .. 12287
  int l  = id & 63, fi = id >> 6;            // fi in [0,192)
  int nt = fi & 3;
  int k6 = (fi >> 2) % 6;
  int w  = fi / 24;
  int row = w*64 + nt*16 + (l & 15);
  int col = kst[k6]*32 + (l >> 4)*8;
  *(bf16x8*)&Wt[(long)id * 8] = *(const bf16x8*)&Whh[row*512 + col];
}

// ---------------------------------------------------------------------------
// Generic C[r,c] = act(A @ W^T + bias (+bias2) (+addsrc)),  C is ROWSx512.
// 128x128 tile, BK=64, 4 waves (2x2 of 64x64), mfma_f32_16x16x32_bf16.
// out_f32: write C as float (final output), else bf16.
// ---------------------------------------------------------------------------
__global__ __launch_bounds__(256, 2) void gemm_k(
    const unsigned short* __restrict__ A, int lda,
    const unsigned short* __restrict__ W, int ldb,
    const unsigned short* __restrict__ bias,
    const unsigned short* __restrict__ bias2,
    const unsigned short* __restrict__ addsrc,
    void* __restrict__ C,
    int K, int act, int out_f32)
{
  __shared__ unsigned short As[128*64];
  __shared__ unsigned short Bs[128*64];
  const int tid = threadIdx.x, w = tid >> 6, l = tid & 63;
  const int wm = w >> 1, wn = w & 1;
  const int lr = l & 15, lk = (l >> 4) * 8;
  const long row0 = (long)blockIdx.x * 128;
  const int  col0 = blockIdx.y * 128;

  f32x4 acc[4][4] = {};

  for (int k0 = 0; k0 < K; k0 += 64){
    __syncthreads();
    #pragma unroll
    for (int i = 0; i < 4; i++){
      int chunk = i*256 + tid;
      int r = chunk >> 3, kc = (chunk & 7) * 8;
      gl_lds16(A + (row0 + r)*lda + k0 + kc, (unsigned short*)As + (i*256 + w*64)*8);
      gl_lds16(W + (long)(col0 + r)*ldb + k0 + kc, (unsigned short*)Bs + (i*256 + w*64)*8);
    }
    asm volatile("s_waitcnt vmcnt(0)" ::: "memory");
    __syncthreads();
    #pragma unroll
    for (int ks = 0; ks < 2; ks++){
      bf16x8 a[4], b[4];
      #pragma unroll
      for (int mt = 0; mt < 4; mt++) a[mt] = *(const bf16x8*)&As[(wm*64 + mt*16 + lr)*64 + ks*32 + lk];
      #pragma unroll
      for (int nt = 0; nt < 4; nt++) b[nt] = *(const bf16x8*)&Bs[(wn*64 + nt*16 + lr)*64 + ks*32 + lk];
      #pragma unroll
      for (int mt = 0; mt < 4; mt++)
        #pragma unroll
        for (int nt = 0; nt < 4; nt++)
          acc[mt][nt] = __builtin_amdgcn_mfma_f32_16x16x32_bf16(a[mt], b[nt], acc[mt][nt], 0, 0, 0);
    }
  }

  #pragma unroll
  for (int nt = 0; nt < 4; nt++){
    int c = col0 + wn*64 + nt*16 + lr;
    float bv = bf2f(bias[c]);
    if (bias2) bv += bf2f(bias2[c]);
    #pragma unroll
    for (int mt = 0; mt < 4; mt++){
      #pragma unroll
      for (int i = 0; i < 4; i++){
        long r = row0 + wm*64 + mt*16 + (l >> 4)*4 + i;
        float v = acc[mt][nt][i] + bv;
        if (addsrc) v += bf2f(addsrc[r*512 + c]);
        if (act) v = fmaxf(v, 0.f);
        if (out_f32) ((float*)C)[r*512 + c] = v;
        else ((unsigned short*)C)[r*512 + c] = f2bf(v);
      }
    }
  }
}

// ---------------------------------------------------------------------------
// Recurrence v4: h_t = tanh(x_ih[:,t,:] + h_{t-1} @ W_hh^T), H[:,t,:] = h_t.
// 16 blocks x 16 batch rows, 512 threads (8 waves x 64 cols).
// Changes vs v3 (was LDS-serialization-bound at ~5900 cyc/step):
//  * W_hh K-slices {0,1,3,4,6,7,9,10,12,13} in registers (wa[4][10], 160 VGPR);
//    slices {2,5,8,11,14,15} stream per-step from fragment-ordered global Wt
//    (L2-resident, coalesced) double-buffered in af0/af1 -> LDS b128 reads/wave
//    drop 34 -> 16. MFMA K-order stays ascending 0..15 => bit-identical math.
//  * h exchange tile double-buffered (2x16x520) -> ONE barrier per step.
//  * h_t stored to H directly from registers (L2 merges the 128B lines).
//  * v_cvt_pk_bf16_f32 packing + clamp-free tanh (both bit-identical, ~40% VALU cut).
// ---------------------------------------------------------------------------
__global__ __launch_bounds__(512, 2) void recur_k(
    const unsigned short* __restrict__ xih,   // (B,T,512) bf16
    const unsigned short* __restrict__ Whh,   // (512,512) bf16
    const unsigned short* __restrict__ Wt,    // fragment-ordered W_hh tail
    unsigned short* __restrict__ H)           // (B,T,512) bf16
{
  __shared__ unsigned short hb[2][16*520];    // 33,280 B

  const int tid = threadIdx.x, w = tid >> 6, l = tid & 63;
  const int lr = l & 15, hi = l >> 4, lk = hi * 8;
  const int b0 = blockIdx.x * 16;
  const int cbase = w * 64;

  // Register-resident A-frags: this wave's 64 cols, K-slices {0,1,3,4,6,7,9,10,12,13}.
  static const int ksl[10] = {0, 1, 3, 4, 6, 7, 9, 10, 12, 13};
  bf16x8 wa[4][10];
  #pragma unroll
  for (int nt = 0; nt < 4; nt++){
    const unsigned short* wp = Whh + (cbase + nt*16 + lr)*512 + lk;
    #pragma unroll
    for (int j = 0; j < 10; j++)
      wa[nt][j] = *(const bf16x8*)&wp[ksl[j]*32];
  }

  // Zero h_0 tile (buffer 0 only; buffer 1 is written before first read).
  for (int i = tid; i < 16*520; i += 512) hb[0][i] = 0;

  const unsigned short* wtb = Wt + (long)w*12288 + l*8;   // + ks6*2048 + nt*512

  const unsigned short* h0 = &hb[0][lr*520 + lk];          // + ks*32
  const unsigned short* h1 = &hb[1][lr*520 + lk];
  unsigned short* w0 = &hb[0][lr*520 + cbase + hi*4];      // + nt*16
  unsigned short* w1 = &hb[1][lr*520 + cbase + hi*4];

  __syncthreads();

  const long xbase = ((long)(b0 + lr) * RT) * 512 + cbase + hi*4;
  const unsigned short* xr = xih + xbase;
  unsigned short*       hr = H   + xbase;

  int cur = 0;
  for (int t = 0; t < RT; t++){
    // Opaque copy of the Wt base: stops LICM from hoisting all 24 frag loads
    // (96 VGPR) out of the loop and spilling.
    const unsigned short* wtp;
    { unsigned long long u = (unsigned long long)wtb;
      asm volatile("" : "+v"(u));
      wtp = (const unsigned short*)u; }

    bf16x8 af0[4], af1[4];
#define LG(A, K6) { const unsigned short* bp = wtp + (K6)*2048; \
      A[0] = *(const bf16x8*)(bp);        A[1] = *(const bf16x8*)(bp + 512); \
      A[2] = *(const bf16x8*)(bp + 1024); A[3] = *(const bf16x8*)(bp + 1536); }
    LG(af0, 0);            // K-slice 2
    LG(af1, 1);            // K-slice 5

    uint2 xu[4];
    #pragma unroll
    for (int nt = 0; nt < 4; nt++)
      xu[nt] = *(const uint2*)(xr + nt*16);

    const unsigned short* hc = cur ? h1 : h0;
    f32x4 acc[4] = {};
#define MM(A, K) { bf16x8 hf = *(const bf16x8*)(hc + (K)*32); \
      acc[0] = __builtin_amdgcn_mfma_f32_16x16x32_bf16(A, hf, acc[0], 0, 0, 0); \
      acc[1] = __builtin_amdgcn_mfma_f32_16x16x32_bf16(A##x, hf, acc[1], 0, 0, 0); }
#define MR(J, K) { bf16x8 hf = *(const bf16x8*)(hc + (K)*32); \
      acc[0] = __builtin_amdgcn_mfma_f32_16x16x32_bf16(wa[0][J], hf, acc[0], 0, 0, 0); \
      acc[1] = __builtin_amdgcn_mfma_f32_16x16x32_bf16(wa[1][J], hf, acc[1], 0, 0, 0); \
      acc[2] = __builtin_amdgcn_mfma_f32_16x16x32_bf16(wa[2][J], hf, acc[2], 0, 0, 0); \
      acc[3] = __builtin_amdgcn_mfma_f32_16x16x32_bf16(wa[3][J], hf, acc[3], 0, 0, 0); }
#define MG(A, K) { bf16x8 hf = *(const bf16x8*)(hc + (K)*32); \
      acc[0] = __builtin_amdgcn_mfma_f32_16x16x32_bf16(A[0], hf, acc[0], 0, 0, 0); \
      acc[1] = __builtin_amdgcn_mfma_f32_16x16x32_bf16(A[1], hf, acc[1], 0, 0, 0); \
      acc[2] = __builtin_amdgcn_mfma_f32_16x16x32_bf16(A[2], hf, acc[2], 0, 0, 0); \
      acc[3] = __builtin_amdgcn_mfma_f32_16x16x32_bf16(A[3], hf, acc[3], 0, 0, 0); }

    // Ascending K order 0..15 (bit-identical accumulation); global slices
    // interleaved with >=3-position prefetch distance for L2 latency.
    MR(0, 0);  MR(1, 1);
    MG(af0, 2);   LG(af0, 2);     // consume K2,  fetch K8
    MR(2, 3);  MR(3, 4);
    MG(af1, 5);   LG(af1, 3);     // consume K5,  fetch K11
    MR(4, 6);  MR(5, 7);
    MG(af0, 8);   LG(af0, 4);     // consume K8,  fetch K14
    MR(6, 9);  MR(7, 10);
    MG(af1, 11);  LG(af1, 5);     // consume K11, fetch K15
    MR(8, 12); MR(9, 13);
    MG(af0, 14);
    MG(af1, 15);
#undef MR
#undef MG
#undef MM
#undef LG

    // h_new = tanh(acc + x_ih); pack to bf16 pairs (RNE) and write exchange tile.
    unsigned short* hw = cur ? w0 : w1;
    uint2 P[4];
    #pragma unroll
    for (int nt = 0; nt < 4; nt++){
      float v0 = tanh_fast(acc[nt][0] + blo(xu[nt].x));
      float v1 = tanh_fast(acc[nt][1] + bhi(xu[nt].x));
      float v2 = tanh_fast(acc[nt][2] + blo(xu[nt].y));
      float v3 = tanh_fast(acc[nt][3] + bhi(xu[nt].y));
      P[nt].x = cvt_pk_bf16(v0, v1);
      P[nt].y = cvt_pk_bf16(v2, v3);
      *(uint2*)(hw + nt*16) = P[nt];
    }

    __syncthreads();   // h_t visible; also orders next step's writes after all reads

    // Direct store of h_t (each 128B line fully covered by one wave -> L2 merge).
    #pragma unroll
    for (int nt = 0; nt < 4; nt++)
      *(uint2*)(hr + nt*16) = P[nt];

    xr += 512; hr += 512;
    cur ^= 1;
  }
}

// ---------------------------------------------------------------------------
// Fused blend: gate = sigmoid([x|h]@W_g^T + b_g); x_proj = x@W_ip^T + b_ip;
// h_proj = h@W_hp^T + b_hp; out = gate*h_proj + (1-gate)*x_proj.
// Two-phase K=768 (phase1: x/K=256 with acc_p=x_proj snapshot; phase2: h/K=512).
// ---------------------------------------------------------------------------
__global__ __launch_bounds__(256, 2) void blend_k(
    const unsigned short* __restrict__ X,    // (ROWS,256) bf16
    const unsigned short* __restrict__ Hm,   // (ROWS,512) bf16
    const unsigned short* __restrict__ Wg,   // (512,768) bf16
    const unsigned short* __restrict__ Wip,  // (512,256) bf16
    const unsigned short* __restrict__ Whp,  // (512,512) bf16
    const unsigned short* __restrict__ bg,
    const unsigned short* __restrict__ bip,
    const unsigned short* __restrict__ bhp,
    unsigned short* __restrict__ Out)
{
  __shared__ unsigned short As[128*64];
  __shared__ unsigned short Gs[128*64];
  __shared__ unsigned short Ps[128*64];
  const int tid = threadIdx.x, w = tid >> 6, l = tid & 63;
  const int wm = w >> 1, wn = w & 1;
  const int lr = l & 15, lk = (l >> 4) * 8;
  const long row0 = (long)blockIdx.x * 128;
  const int  col0 = blockIdx.y * 128;

  f32x4 accg[4][4] = {}, accp[4][4] = {};
  unsigned int xpp[4][4][2];

  #pragma unroll 1
  for (int k0 = 0; k0 < 768; k0 += 64){
    const bool ph1 = (k0 < 256);
    __syncthreads();
    #pragma unroll
    for (int i = 0; i < 4; i++){
      int chunk = i*256 + tid;
      int r = chunk >> 3, kc = (chunk & 7) * 8;
      const unsigned short* asrc = ph1 ? (X  + (row0 + r)*256 + k0 + kc)
                                       : (Hm + (row0 + r)*512 + (k0 - 256) + kc);
      gl_lds16(asrc, (unsigned short*)As + (i*256 + w*64)*8);
      gl_lds16(Wg + (long)(col0 + r)*768 + k0 + kc, (unsigned short*)Gs + (i*256 + w*64)*8);
      const unsigned short* psrc = ph1 ? (Wip + (col0 + r)*256 + k0 + kc)
                                       : (Whp + (col0 + r)*512 + (k0 - 256) + kc);
      gl_lds16(psrc, (unsigned short*)Ps + (i*256 + w*64)*8);
    }
    asm volatile("s_waitcnt vmcnt(0)" ::: "memory");
    __syncthreads();
    #pragma unroll
    for (int ks = 0; ks < 2; ks++){
      bf16x8 a[4], gq[4], pq[4];
      #pragma unroll
      for (int mt = 0; mt < 4; mt++) a[mt]  = *(const bf16x8*)&As[(wm*64 + mt*16 + lr)*64 + ks*32 + lk];
      #pragma unroll
      for (int nt = 0; nt < 4; nt++){
        gq[nt] = *(const bf16x8*)&Gs[(wn*64 + nt*16 + lr)*64 + ks*32 + lk];
        pq[nt] = *(const bf16x8*)&Ps[(wn*64 + nt*16 + lr)*64 + ks*32 + lk];
      }
      #pragma unroll
      for (int mt = 0; mt < 4; mt++)
        #pragma unroll
        for (int nt = 0; nt < 4; nt++){
          accg[mt][nt] = __builtin_amdgcn_mfma_f32_16x16x32_bf16(a[mt], gq[nt], accg[mt][nt], 0, 0, 0);
          accp[mt][nt] = __builtin_amdgcn_mfma_f32_16x16x32_bf16(a[mt], pq[nt], accp[mt][nt], 0, 0, 0);
        }
    }
    if (k0 == 192){   // end of phase 1: snapshot x_proj, reset acc_p for h_proj
      #pragma unroll
      for (int mt = 0; mt < 4; mt++)
        #pragma unroll
        for (int nt = 0; nt < 4; nt++){
          xpp[mt][nt][0] = (unsigned)f2bf(accp[mt][nt][0]) | ((unsigned)f2bf(accp[mt][nt][1]) << 16);
          xpp[mt][nt][1] = (unsigned)f2bf(accp[mt][nt][2]) | ((unsigned)f2bf(accp[mt][nt][3]) << 16);
          accp[mt][nt] = (f32x4){0.f, 0.f, 0.f, 0.f};
        }
    }
  }

  #pragma unroll
  for (int nt = 0; nt < 4; nt++){
    int c = col0 + wn*64 + nt*16 + lr;
    float bgv = bf2f(bg[c]), bipv = bf2f(bip[c]), bhpv = bf2f(bhp[c]);
    #pragma unroll
    for (int mt = 0; mt < 4; mt++){
      #pragma unroll
      for (int i = 0; i < 4; i++){
        long r = row0 + wm*64 + mt*16 + (l >> 4)*4 + i;
        float g  = sigmoid_fast(accg[mt][nt][i] + bgv);
        float hp = accp[mt][nt][i] + bhpv;
        unsigned u = xpp[mt][nt][i >> 1];
        float xp = bf2f((unsigned short)((i & 1) ? (u >> 16) : (u & 0xffff))) + bipv;
        float v = g * hp + (1.f - g) * xp;
        Out[r*512 + c] = f2bf(v);
      }
    }
  }
}

// ---------------------------------------------------------------------------
// Buffer plan. d_out (268 MB, f32 final) doubles as bf16 scratch; W_o/b_o
// live in d_ws so K5 never reads what it writes:
//   d_out [0, 64Mi):         x_bf16 (67.1 MB)
//   d_out [64Mi, +2.9MB):    converted weights W_ih..b_r
//   d_out [72Mi, +134MB):    x_ih, later blended (bf16)  [ends at 209,715,200)
//   d_out [209,715,200, +196KB): Wt (fragment-ordered W_hh tail)
//   d_ws  [0, 134MB):        H, later u (bf16)
//   d_ws  [134MB, +525KB):   W_o, b_o (bf16)
// conv -> wtail -> K1(x_ih) -> K2(H) -> K3(blended) -> K4(u) -> K5(f32 out).
// Every stage's read set is disjoint from its write set.
// ---------------------------------------------------------------------------
extern "C" void kernel_launch(void* const* d_in, const int* in_sizes, int n_in,
                              void* d_out, int out_size, void* d_ws, size_t ws_size,
                              hipStream_t stream)
{
  static const long nelem[15] = {
    (long)ROWS*256,        // x
    512*256, 512,          // W_ih, b_ih
    512*512, 512,          // W_hh, b_hh
    512*256, 512,          // W_ip, b_ip
    512*512, 512,          // W_hp, b_hp
    512*768, 512,          // W_g,  b_g
    512*512, 512,          // W_r,  b_r
    512*512, 512           // W_o,  b_o
  };

  unsigned char* ob = (unsigned char*)d_out;
  unsigned char* wb = (unsigned char*)d_ws;
  ConvArgs ca;
  long pre = 0;
  size_t doff = 0;
  for (int i = 0; i < 15; i++){
    ca.src[i] = (const float*)d_in[i];
    if (i == 13)      ca.dst[i] = (unsigned short*)(wb + 134217728u);   // W_o
    else if (i == 14) ca.dst[i] = (unsigned short*)(wb + 134742016u);   // b_o
    else              ca.dst[i] = (unsigned short*)(ob + doff);
    ca.pre[i] = pre;
    pre += nelem[i] / 4;
    if (i == 0) doff = 67108864u;
    else if (i < 13) doff += (size_t)nelem[i] * 2;
  }
  ca.pre[15] = pre;
  const long total_chunks = pre;   // 8,815,488

  const unsigned short* xb  = ca.dst[0];
  const unsigned short* Wih = ca.dst[1];
  const unsigned short* bih = ca.dst[2];
  const unsigned short* Whh = ca.dst[3];
  const unsigned short* bhh = ca.dst[4];
  const unsigned short* Wip = ca.dst[5];
  const unsigned short* bip = ca.dst[6];
  const unsigned short* Whp = ca.dst[7];
  const unsigned short* bhp = ca.dst[8];
  const unsigned short* Wg  = ca.dst[9];
  const unsigned short* bg  = ca.dst[10];
  const unsigned short* Wr  = ca.dst[11];
  const unsigned short* br  = ca.dst[12];
  const unsigned short* Wo  = ca.dst[13];
  const unsigned short* bo  = ca.dst[14];

  unsigned short* xih  = (unsigned short*)(ob + 75497472u);    // 72 MiB offset
  unsigned short* Wtl  = (unsigned short*)(ob + 209715200u);   // W_hh tail frags
  unsigned short* wsb  = (unsigned short*)d_ws;                // H, later u

  dim3 grid(ROWS / 128, 4), block(256);

  // K0: convert all f32 inputs to bf16.
  conv_k<<<2048, 256, 0, stream>>>(ca, total_chunks);

  // K0b: repack W_hh tail slices into fragment order for recur_k.
  wtail_k<<<48, 256, 0, stream>>>(Whh, Wtl);

  // K1: x_ih = x @ W_ih^T + b_ih + b_hh  -> xih (bf16)
  gemm_k<<<grid, block, 0, stream>>>(xb, 256, Wih, 256, bih, bhh, nullptr, xih, 256, 0, 0);

  // K2: recurrence -> H in ws (16 blocks x 512 threads, 33 KB static LDS)
  recur_k<<<16, 512, 0, stream>>>(xih, Whh, Wtl, wsb);

  // K3: blended (fused gate/x_proj/h_proj) -> xih region (x_ih dead)
  blend_k<<<grid, block, 0, stream>>>(xb, wsb, Wg, Wip, Whp, bg, bip, bhp, xih);

  // K4: u = relu(blended @ W_r^T + b_r + blended) -> ws (H dead)
  gemm_k<<<grid, block, 0, stream>>>(xih, 512, Wr, 512, br, nullptr, xih, wsb, 512, 1, 0);

  // K5: out = u @ W_o^T + b_o -> d_out (f32; reads only from d_ws)
  gemm_k<<<grid, block, 0, stream>>>(wsb, 512, Wo, 512, bo, nullptr, nullptr, d_out, 512, 0, 1);
}

// Round 2
// 2103.100 us; speedup vs baseline: 1.5081x; 1.5081x over previous
//
#include <hip/hip_runtime.h>
#include <hip/hip_bf16.h>
#include <cstdint>

// B=256, T=512, D_IN=256, D_H=512, D_P=512. Inputs/outputs are FLOAT32.
// Internals run in bf16 MFMA with f32 accumulate.
#define RB   256
#define RT   512
#define ROWS (RB*RT)   // 131072

typedef __attribute__((ext_vector_type(8))) short bf16x8;
typedef __attribute__((ext_vector_type(4))) short s16x4;
typedef __attribute__((ext_vector_type(4))) float f32x4;

#define DEV static __device__ __forceinline__

DEV float bf2f(unsigned short u){
  union { unsigned int i; float f; } v; v.i = ((unsigned int)u) << 16; return v.f;
}
DEV float blo(unsigned int u){
  union { unsigned int i; float f; } v; v.i = u << 16; return v.f;
}
DEV float bhi(unsigned int u){
  union { unsigned int i; float f; } v; v.i = u & 0xffff0000u; return v.f;
}
DEV unsigned short f2bf(float f){
  union { float f; unsigned int i; } v; v.f = f;
  unsigned int x = v.i;
  return (unsigned short)((x + 0x7fffu + ((x >> 16) & 1u)) >> 16);   // RNE
}
DEV unsigned int cvt_pk_bf16(float lo, float hi){   // RNE, bit-identical to f2bf
  unsigned int r;
  asm("v_cvt_pk_bf16_f32 %0, %1, %2" : "=v"(r) : "v"(lo), "v"(hi));
  return r;
}
DEV float tanh_fast(float x){
  // No clamp needed: e=inf -> rcp=0 -> 1.0; e=0 -> rcp(1)=1 -> -1.0 (exact saturation).
  float e  = __expf(2.f * x);
  return 1.f - 2.f * __builtin_amdgcn_rcpf(e + 1.f);
}
DEV float sigmoid_fast(float x){
  float xc = fminf(fmaxf(x, -30.f), 30.f);
  return __builtin_amdgcn_rcpf(1.f + __expf(-xc));
}
DEV void gl_lds16(const void* g, void* l){
  __builtin_amdgcn_global_load_lds(
      (const __attribute__((address_space(1))) unsigned int*)g,
      (__attribute__((address_space(3))) unsigned int*)l, 16, 0, 0);
}

// ---------------------------------------------------------------------------
// f32 -> bf16 conversion of all 15 input tensors (one launch, 4 elems/thread).
// ---------------------------------------------------------------------------
struct ConvArgs {
  const float* src[15];
  unsigned short* dst[15];
  long pre[16];          // prefix sums in 4-element chunks
};

__global__ __launch_bounds__(256) void conv_k(ConvArgs a, long total)
{
  long stride = (long)gridDim.x * blockDim.x;
  for (long idx = (long)blockIdx.x * blockDim.x + threadIdx.x; idx < total; idx += stride){
    int t = 0;
    #pragma unroll
    for (int j = 0; j < 14; j++) t += (idx >= a.pre[j + 1]) ? 1 : 0;
    long local = idx - a.pre[t];
    float4 v = ((const float4*)a.src[t])[local];
    s16x4 o;
    o[0] = (short)f2bf(v.x); o[1] = (short)f2bf(v.y);
    o[2] = (short)f2bf(v.z); o[3] = (short)f2bf(v.w);
    ((s16x4*)a.dst[t])[local] = o;
  }
}

// ---------------------------------------------------------------------------
// Generic C[r,c] = act(A @ W^T + bias (+bias2) (+addsrc)),  C is ROWSx512.
// 128x128 tile, BK=64, 4 waves (2x2 of 64x64), mfma_f32_16x16x32_bf16.
// out_f32: write C as float (final output), else bf16.
// ---------------------------------------------------------------------------
__global__ __launch_bounds__(256, 2) void gemm_k(
    const unsigned short* __restrict__ A, int lda,
    const unsigned short* __restrict__ W, int ldb,
    const unsigned short* __restrict__ bias,
    const unsigned short* __restrict__ bias2,
    const unsigned short* __restrict__ addsrc,
    void* __restrict__ C,
    int K, int act, int out_f32)
{
  __shared__ unsigned short As[128*64];
  __shared__ unsigned short Bs[128*64];
  const int tid = threadIdx.x, w = tid >> 6, l = tid & 63;
  const int wm = w >> 1, wn = w & 1;
  const int lr = l & 15, lk = (l >> 4) * 8;
  const long row0 = (long)blockIdx.x * 128;
  const int  col0 = blockIdx.y * 128;

  f32x4 acc[4][4] = {};

  for (int k0 = 0; k0 < K; k0 += 64){
    __syncthreads();
    #pragma unroll
    for (int i = 0; i < 4; i++){
      int chunk = i*256 + tid;
      int r = chunk >> 3, kc = (chunk & 7) * 8;
      gl_lds16(A + (row0 + r)*lda + k0 + kc, (unsigned short*)As + (i*256 + w*64)*8);
      gl_lds16(W + (long)(col0 + r)*ldb + k0 + kc, (unsigned short*)Bs + (i*256 + w*64)*8);
    }
    asm volatile("s_waitcnt vmcnt(0)" ::: "memory");
    __syncthreads();
    #pragma unroll
    for (int ks = 0; ks < 2; ks++){
      bf16x8 a[4], b[4];
      #pragma unroll
      for (int mt = 0; mt < 4; mt++) a[mt] = *(const bf16x8*)&As[(wm*64 + mt*16 + lr)*64 + ks*32 + lk];
      #pragma unroll
      for (int nt = 0; nt < 4; nt++) b[nt] = *(const bf16x8*)&Bs[(wn*64 + nt*16 + lr)*64 + ks*32 + lk];
      #pragma unroll
      for (int mt = 0; mt < 4; mt++)
        #pragma unroll
        for (int nt = 0; nt < 4; nt++)
          acc[mt][nt] = __builtin_amdgcn_mfma_f32_16x16x32_bf16(a[mt], b[nt], acc[mt][nt], 0, 0, 0);
    }
  }

  #pragma unroll
  for (int nt = 0; nt < 4; nt++){
    int c = col0 + wn*64 + nt*16 + lr;
    float bv = bf2f(bias[c]);
    if (bias2) bv += bf2f(bias2[c]);
    #pragma unroll
    for (int mt = 0; mt < 4; mt++){
      #pragma unroll
      for (int i = 0; i < 4; i++){
        long r = row0 + wm*64 + mt*16 + (l >> 4)*4 + i;
        float v = acc[mt][nt][i] + bv;
        if (addsrc) v += bf2f(addsrc[r*512 + c]);
        if (act) v = fmaxf(v, 0.f);
        if (out_f32) ((float*)C)[r*512 + c] = v;
        else ((unsigned short*)C)[r*512 + c] = f2bf(v);
      }
    }
  }
}

// ---------------------------------------------------------------------------
// Recurrence v5: h_t = tanh(x_ih[:,t,:] + h_{t-1} @ W_hh^T), H[:,t,:] = h_t.
// 16 blocks x 16 batch rows, 512 threads (8 waves x 64 cols).
// v3 structure (W_hh K[0,384) in regs, K[384,512) in LDS, single h tile,
// 2 barriers) with the v3 bug FIXED: the wa fragments are PINNED via empty
// inline asm so LLVM cannot rematerialize the global loads inside the t-loop
// (v3/v4 reported VGPR_Count=120..128 < the 192 needed => weights were being
// re-loaded from L2 every step; that was the real bottleneck).
// Also kept from v4 (bit-identical): v_cvt_pk_bf16_f32 packing, clamp-free
// tanh, direct register->global H stores.
// ---------------------------------------------------------------------------
__global__ __launch_bounds__(512, 2) void recur_k(
    const unsigned short* __restrict__ xih,   // (B,T,512) bf16
    const unsigned short* __restrict__ Whh,   // (512,512) bf16
    unsigned short* __restrict__ H)           // (B,T,512) bf16
{
  extern __shared__ unsigned short lds[];
  unsigned short* Wl = lds;                 // [512][136]: W_hh cols, K[384,512)
  unsigned short* hb = lds + 512*136;       // [16][520]: h exchange tile

  const int tid = threadIdx.x, w = tid >> 6, l = tid & 63;
  const int lr = l & 15, hi = l >> 4, lk = hi * 8;
  const int b0 = blockIdx.x * 16;
  const int cbase = w * 64;

  // Stage W_hh K[384,512) into LDS: 512 rows x 128 ushorts (pad to 136).
  #pragma unroll
  for (int i = 0; i < 16; i++){
    int id = i*512 + tid;                   // 8192 b128 chunks
    int c = id >> 4, j = (id & 15) * 8;
    *(bf16x8*)&Wl[c*136 + j] = *(const bf16x8*)&Whh[c*512 + 384 + j];
  }
  // Zero h tile (h0 = 0).
  for (int i = tid; i < 16*520; i += 512) hb[i] = 0;

  // Register-resident A-frags: this wave's 64 cols, K[0,384).
  // PIN each fragment: asm results are not rematerializable, forcing true
  // register residency (192 VGPR) instead of per-step L2 reloads.
  bf16x8 wa[4][12];
  #pragma unroll
  for (int nt = 0; nt < 4; nt++){
    const unsigned short* wp = Whh + (cbase + nt*16 + lr)*512 + lk;
    #pragma unroll
    for (int ks = 0; ks < 12; ks++)
      wa[nt][ks] = *(const bf16x8*)&wp[ks*32];
  }
  #pragma unroll
  for (int nt = 0; nt < 4; nt++)
    #pragma unroll
    for (int ks = 0; ks < 12; ks++)
      asm volatile("" : "+v"(wa[nt][ks]));

  __syncthreads();

  // Precomputed LDS byte bases.
  const unsigned short* hrd = &hb[lr*520 + lk];                 // + ks*32
  const unsigned short* wlb = &Wl[(cbase + lr)*136 + lk];       // + nt*16*136 + ks4*32
  unsigned short*       hwr = &hb[lr*520 + cbase + hi*4];       // + nt*16

  const long xbase = ((long)(b0 + lr) * RT) * 512 + cbase + hi*4;
  const unsigned short* xr = xih + xbase;
  unsigned short*       hr = H   + xbase;

  #pragma unroll 1
  for (int t = 0; t < RT; t++){
    uint2 xu[4];
    #pragma unroll
    for (int nt = 0; nt < 4; nt++)
      xu[nt] = *(const uint2*)(xr + nt*16);

    f32x4 acc[4] = {};
    // K-slices 0..11 from pinned registers (ascending K: bit-identical).
    #pragma unroll
    for (int ks = 0; ks < 12; ks++){
      bf16x8 hf = *(const bf16x8*)(hrd + ks*32);
      #pragma unroll
      for (int nt = 0; nt < 4; nt++)
        acc[nt] = __builtin_amdgcn_mfma_f32_16x16x32_bf16(wa[nt][ks], hf, acc[nt], 0, 0, 0);
    }
    // K-slices 12..15 from LDS.
    #pragma unroll
    for (int ks = 0; ks < 4; ks++){
      bf16x8 hf = *(const bf16x8*)(hrd + (12 + ks)*32);
      #pragma unroll
      for (int nt = 0; nt < 4; nt++){
        bf16x8 af = *(const bf16x8*)(wlb + (nt*16)*136 + ks*32);
        acc[nt] = __builtin_amdgcn_mfma_f32_16x16x32_bf16(af, hf, acc[nt], 0, 0, 0);
      }
    }

    // h_new = tanh(acc + x_ih); pack to bf16 pairs (RNE).
    uint2 P[4];
    #pragma unroll
    for (int nt = 0; nt < 4; nt++){
      float v0 = tanh_fast(acc[nt][0] + blo(xu[nt].x));
      float v1 = tanh_fast(acc[nt][1] + bhi(xu[nt].x));
      float v2 = tanh_fast(acc[nt][2] + blo(xu[nt].y));
      float v3 = tanh_fast(acc[nt][3] + bhi(xu[nt].y));
      P[nt].x = cvt_pk_bf16(v0, v1);
      P[nt].y = cvt_pk_bf16(v2, v3);
    }

    // Direct store of h_t to H (global; no LDS staging).
    #pragma unroll
    for (int nt = 0; nt < 4; nt++)
      *(uint2*)(hr + nt*16) = P[nt];

    __syncthreads();   // A: all waves done reading h_{t-1}
    #pragma unroll
    for (int nt = 0; nt < 4; nt++)
      *(uint2*)(hwr + nt*16) = P[nt];
    __syncthreads();   // B: h_t visible

    xr += 512; hr += 512;
  }
}

// ---------------------------------------------------------------------------
// Fused blend: gate = sigmoid([x|h]@W_g^T + b_g); x_proj = x@W_ip^T + b_ip;
// h_proj = h@W_hp^T + b_hp; out = gate*h_proj + (1-gate)*x_proj.
// Two-phase K=768 (phase1: x/K=256 with acc_p=x_proj snapshot; phase2: h/K=512).
// ---------------------------------------------------------------------------
__global__ __launch_bounds__(256, 2) void blend_k(
    const unsigned short* __restrict__ X,    // (ROWS,256) bf16
    const unsigned short* __restrict__ Hm,   // (ROWS,512) bf16
    const unsigned short* __restrict__ Wg,   // (512,768) bf16
    const unsigned short* __restrict__ Wip,  // (512,256) bf16
    const unsigned short* __restrict__ Whp,  // (512,512) bf16
    const unsigned short* __restrict__ bg,
    const unsigned short* __restrict__ bip,
    const unsigned short* __restrict__ bhp,
    unsigned short* __restrict__ Out)
{
  __shared__ unsigned short As[128*64];
  __shared__ unsigned short Gs[128*64];
  __shared__ unsigned short Ps[128*64];
  const int tid = threadIdx.x, w = tid >> 6, l = tid & 63;
  const int wm = w >> 1, wn = w & 1;
  const int lr = l & 15, lk = (l >> 4) * 8;
  const long row0 = (long)blockIdx.x * 128;
  const int  col0 = blockIdx.y * 128;

  f32x4 accg[4][4] = {}, accp[4][4] = {};
  unsigned int xpp[4][4][2];

  #pragma unroll 1
  for (int k0 = 0; k0 < 768; k0 += 64){
    const bool ph1 = (k0 < 256);
    __syncthreads();
    #pragma unroll
    for (int i = 0; i < 4; i++){
      int chunk = i*256 + tid;
      int r = chunk >> 3, kc = (chunk & 7) * 8;
      const unsigned short* asrc = ph1 ? (X  + (row0 + r)*256 + k0 + kc)
                                       : (Hm + (row0 + r)*512 + (k0 - 256) + kc);
      gl_lds16(asrc, (unsigned short*)As + (i*256 + w*64)*8);
      gl_lds16(Wg + (long)(col0 + r)*768 + k0 + kc, (unsigned short*)Gs + (i*256 + w*64)*8);
      const unsigned short* psrc = ph1 ? (Wip + (col0 + r)*256 + k0 + kc)
                                       : (Whp + (col0 + r)*512 + (k0 - 256) + kc);
      gl_lds16(psrc, (unsigned short*)Ps + (i*256 + w*64)*8);
    }
    asm volatile("s_waitcnt vmcnt(0)" ::: "memory");
    __syncthreads();
    #pragma unroll
    for (int ks = 0; ks < 2; ks++){
      bf16x8 a[4], gq[4], pq[4];
      #pragma unroll
      for (int mt = 0; mt < 4; mt++) a[mt]  = *(const bf16x8*)&As[(wm*64 + mt*16 + lr)*64 + ks*32 + lk];
      #pragma unroll
      for (int nt = 0; nt < 4; nt++){
        gq[nt] = *(const bf16x8*)&Gs[(wn*64 + nt*16 + lr)*64 + ks*32 + lk];
        pq[nt] = *(const bf16x8*)&Ps[(wn*64 + nt*16 + lr)*64 + ks*32 + lk];
      }
      #pragma unroll
      for (int mt = 0; mt < 4; mt++)
        #pragma unroll
        for (int nt = 0; nt < 4; nt++){
          accg[mt][nt] = __builtin_amdgcn_mfma_f32_16x16x32_bf16(a[mt], gq[nt], accg[mt][nt], 0, 0, 0);
          accp[mt][nt] = __builtin_amdgcn_mfma_f32_16x16x32_bf16(a[mt], pq[nt], accp[mt][nt], 0, 0, 0);
        }
    }
    if (k0 == 192){   // end of phase 1: snapshot x_proj, reset acc_p for h_proj
      #pragma unroll
      for (int mt = 0; mt < 4; mt++)
        #pragma unroll
        for (int nt = 0; nt < 4; nt++){
          xpp[mt][nt][0] = (unsigned)f2bf(accp[mt][nt][0]) | ((unsigned)f2bf(accp[mt][nt][1]) << 16);
          xpp[mt][nt][1] = (unsigned)f2bf(accp[mt][nt][2]) | ((unsigned)f2bf(accp[mt][nt][3]) << 16);
          accp[mt][nt] = (f32x4){0.f, 0.f, 0.f, 0.f};
        }
    }
  }

  #pragma unroll
  for (int nt = 0; nt < 4; nt++){
    int c = col0 + wn*64 + nt*16 + lr;
    float bgv = bf2f(bg[c]), bipv = bf2f(bip[c]), bhpv = bf2f(bhp[c]);
    #pragma unroll
    for (int mt = 0; mt < 4; mt++){
      #pragma unroll
      for (int i = 0; i < 4; i++){
        long r = row0 + wm*64 + mt*16 + (l >> 4)*4 + i;
        float g  = sigmoid_fast(accg[mt][nt][i] + bgv);
        float hp = accp[mt][nt][i] + bhpv;
        unsigned u = xpp[mt][nt][i >> 1];
        float xp = bf2f((unsigned short)((i & 1) ? (u >> 16) : (u & 0xffff))) + bipv;
        float v = g * hp + (1.f - g) * xp;
        Out[r*512 + c] = f2bf(v);
      }
    }
  }
}

// ---------------------------------------------------------------------------
// Buffer plan. d_out (268 MB, f32 final) doubles as bf16 scratch; W_o/b_o
// live in d_ws so K5 never reads what it writes:
//   d_out [0, 64Mi):        x_bf16 (67.1 MB)
//   d_out [64Mi, +2.9MB):   converted weights W_ih..b_r
//   d_out [72Mi, +134MB):   x_ih, later blended (bf16)
//   d_ws  [0, 134MB):       H, later u (bf16)
//   d_ws  [134MB, +525KB):  W_o, b_o (bf16)
// conv -> K1(x_ih) -> K2(H) -> K3(blended) -> K4(u) -> K5(f32 out).
// Every stage's read set is disjoint from its write set.
// ---------------------------------------------------------------------------
extern "C" void kernel_launch(void* const* d_in, const int* in_sizes, int n_in,
                              void* d_out, int out_size, void* d_ws, size_t ws_size,
                              hipStream_t stream)
{
  static const long nelem[15] = {
    (long)ROWS*256,        // x
    512*256, 512,          // W_ih, b_ih
    512*512, 512,          // W_hh, b_hh
    512*256, 512,          // W_ip, b_ip
    512*512, 512,          // W_hp, b_hp
    512*768, 512,          // W_g,  b_g
    512*512, 512,          // W_r,  b_r
    512*512, 512           // W_o,  b_o
  };

  unsigned char* ob = (unsigned char*)d_out;
  unsigned char* wb = (unsigned char*)d_ws;
  ConvArgs ca;
  long pre = 0;
  size_t doff = 0;
  for (int i = 0; i < 15; i++){
    ca.src[i] = (const float*)d_in[i];
    if (i == 13)      ca.dst[i] = (unsigned short*)(wb + 134217728u);   // W_o
    else if (i == 14) ca.dst[i] = (unsigned short*)(wb + 134742016u);   // b_o
    else              ca.dst[i] = (unsigned short*)(ob + doff);
    ca.pre[i] = pre;
    pre += nelem[i] / 4;
    if (i == 0) doff = 67108864u;
    else if (i < 13) doff += (size_t)nelem[i] * 2;
  }
  ca.pre[15] = pre;
  const long total_chunks = pre;   // 8,815,488

  const unsigned short* xb  = ca.dst[0];
  const unsigned short* Wih = ca.dst[1];
  const unsigned short* bih = ca.dst[2];
  const unsigned short* Whh = ca.dst[3];
  const unsigned short* bhh = ca.dst[4];
  const unsigned short* Wip = ca.dst[5];
  const unsigned short* bip = ca.dst[6];
  const unsigned short* Whp = ca.dst[7];
  const unsigned short* bhp = ca.dst[8];
  const unsigned short* Wg  = ca.dst[9];
  const unsigned short* bg  = ca.dst[10];
  const unsigned short* Wr  = ca.dst[11];
  const unsigned short* br  = ca.dst[12];
  const unsigned short* Wo  = ca.dst[13];
  const unsigned short* bo  = ca.dst[14];

  unsigned short* xih  = (unsigned short*)(ob + 75497472u);   // 72 MiB offset
  unsigned short* wsb  = (unsigned short*)d_ws;               // H, later u

  dim3 grid(ROWS / 128, 4), block(256);

  // K0: convert all f32 inputs to bf16.
  conv_k<<<2048, 256, 0, stream>>>(ca, total_chunks);

  // K1: x_ih = x @ W_ih^T + b_ih + b_hh  -> xih (bf16)
  gemm_k<<<grid, block, 0, stream>>>(xb, 256, Wih, 256, bih, bhh, nullptr, xih, 256, 0, 0);

  // K2: recurrence -> H in ws (16 blocks x 512 threads, 155,904 B dyn LDS)
  static const int kRecurLds = 512*136*2 + 16*520*2;   // 155,904
  hipFuncSetAttribute((const void*)recur_k, hipFuncAttributeMaxDynamicSharedMemorySize, kRecurLds);
  recur_k<<<16, 512, kRecurLds, stream>>>(xih, Whh, wsb);

  // K3: blended (fused gate/x_proj/h_proj) -> xih region (x_ih dead)
  blend_k<<<grid, block, 0, stream>>>(xb, wsb, Wg, Wip, Whp, bg, bip, bhp, xih);

  // K4: u = relu(blended @ W_r^T + b_r + blended) -> ws (H dead)
  gemm_k<<<grid, block, 0, stream>>>(xih, 512, Wr, 512, br, nullptr, xih, wsb, 512, 1, 0);

  // K5: out = u @ W_o^T + b_o -> d_out (f32; reads only from d_ws)
  gemm_k<<<grid, block, 0, stream>>>(wsb, 512, Wo, 512, bo, nullptr, nullptr, d_out, 512, 0, 1);
}